// Round 3
// baseline (181.161 us; speedup 1.0000x reference)
//
#include <hip/hip_runtime.h>
#include <hip/hip_bf16.h>

#define N_NODES 4096
#define IN_DIM 1024
#define OUT_DIM 512
#define NUM_HEADS 4
#define HEAD_DIM 128
#define TOP_K 16
#define NEG_SLOPE 0.2f

typedef __attribute__((ext_vector_type(8))) short bf16x8;
typedef __attribute__((ext_vector_type(4))) float f32x4;

typedef __attribute__((address_space(3))) unsigned as3_u32;
typedef const __attribute__((address_space(1))) unsigned as1_u32;

static __device__ __forceinline__ void gld16(const void* g, void* l) {
    __builtin_amdgcn_global_load_lds((as1_u32*)g, (as3_u32*)l, 16, 0, 0);
}

__device__ __forceinline__ unsigned short f2bf(float f) {
    unsigned u = __float_as_uint(f);
    unsigned r = u + 0x7FFFu + ((u >> 16) & 1u);   // round-to-nearest-even
    return (unsigned short)(r >> 16);
}
__device__ __forceinline__ float bf2f(unsigned short h) {
    return __uint_as_float(((unsigned)h) << 16);
}

// ---------------------------------------------------------------------------
// Prep (fused): f32 -> swizzled hi|lo bf16 for x and W, plus zero-init of
// s_src/s_dst (32768 floats).  Chunk at position c ^ (row&7), row stride 2048.
// ---------------------------------------------------------------------------
__device__ __forceinline__ void conv_row(const float* __restrict__ src,
                                         unsigned short* __restrict__ dst, int t)
{
    int row = t >> 7, rem = t & 127, kb = rem >> 2, c = rem & 3;
    const float* s = src + (size_t)row * IN_DIM + kb * 32 + c * 8;
    float4 v0 = *(const float4*)s;
    float4 v1 = *(const float4*)(s + 4);
    float vv[8] = {v0.x, v0.y, v0.z, v0.w, v1.x, v1.y, v1.z, v1.w};
    bf16x8 H, L;
#pragma unroll
    for (int e = 0; e < 8; ++e) {
        unsigned short h = f2bf(vv[e]);
        H[e] = (short)h;
        L[e] = (short)f2bf(vv[e] - bf2f(h));
    }
    int sw = row & 7;
    unsigned short* base = dst + (size_t)row * 2048 + kb * 64;
    *(bf16x8*)(base + ((c ^ sw) << 3))       = H;
    *(bf16x8*)(base + (((c + 4) ^ sw) << 3)) = L;
}

__global__ __launch_bounds__(256) void prep_kernel(
    const float* __restrict__ x, const float* __restrict__ W,
    unsigned short* __restrict__ xc, unsigned short* __restrict__ wc,
    float* __restrict__ szero)
{
    int b = blockIdx.x, tid = threadIdx.x;
    if (b < 2048) {
        conv_row(x, xc, b * 256 + tid);
    } else if (b < 2304) {
        conv_row(W, wc, (b - 2048) * 256 + tid);
    } else {
        int t = (b - 2304) * 256 + tid;
        ((float4*)szero)[t] = (float4){0.f, 0.f, 0.f, 0.f};
    }
}

// ---------------------------------------------------------------------------
// GEMM + fused attention scores.  Tile 64x64, BK=32, 256 threads = 4 waves
// (cols), double-buffered LDS via global_load_lds(16B), swizzled reads.
// XCD-aware 1-D swizzle: xcd=id&7 gets bm in [8*xcd, 8*xcd+8), all bn ->
// per-XCD working set = 2MB A-panel + 2MB B = 4MB = its L2.
// Epilogue: Wh store + s_src/s_dst partial dots (shfl-reduce + atomicAdd).
// ---------------------------------------------------------------------------
#define GBM 64
#define GBN 64
#define NT  (IN_DIM / 32)    // 32 K-steps

__global__ __launch_bounds__(256) void gemm_kernel(
    const unsigned short* __restrict__ xc, const unsigned short* __restrict__ wc,
    const float* __restrict__ a, float* __restrict__ Wh,
    float* __restrict__ s_src, float* __restrict__ s_dst)
{
    __shared__ __align__(16) unsigned short As[2][GBM * 64];  // 8 KB each
    __shared__ __align__(16) unsigned short Bs[2][GBN * 64];  // 8 KB each

    const int tid = threadIdx.x;
    const int id  = blockIdx.x;
    const int xcd = id & 7, seq = id >> 3;
    const int bm  = xcd * 8 + (seq >> 3), bn = seq & 7;

    const int wn = tid >> 6, lane = tid & 63;
    const int lr = lane & 15, lk = lane >> 4;

    f32x4 acc[4];
#pragma unroll
    for (int i = 0; i < 4; ++i) acc[i] = (f32x4){0.f, 0.f, 0.f, 0.f};

    auto stage = [&](int buf, int kt) {
#pragma unroll
        for (int seg = 0; seg < 2; ++seg) {       // A,B: 512 chunks each
            int ci = seg * 256 + tid;
            int row = ci >> 3, p = ci & 7;
            size_t off = (size_t)kt * 128 + p * 16;
            gld16((const char*)xc + ((size_t)(bm * GBM + row) * 4096 + off),
                  (char*)&As[buf][0] + (size_t)ci * 16);
            gld16((const char*)wc + ((size_t)(bn * GBN + row) * 4096 + off),
                  (char*)&Bs[buf][0] + (size_t)ci * 16);
        }
    };

    stage(0, 0);
    __syncthreads();
    int cur = 0;
    for (int kt = 0; kt < NT; ++kt) {
        if (kt + 1 < NT) stage(cur ^ 1, kt + 1);

        bf16x8 bh, bl;
        {
            int rb = wn * 16 + lr, sw = (rb & 7) << 3;
            bh = *(const bf16x8*)&Bs[cur][rb * 64 + ((lk * 8) ^ sw)];
            bl = *(const bf16x8*)&Bs[cur][rb * 64 + ((32 + lk * 8) ^ sw)];
        }
#pragma unroll
        for (int mi = 0; mi < 4; ++mi) {
            int r = mi * 16 + lr, sw = (r & 7) << 3;
            bf16x8 ah = *(const bf16x8*)&As[cur][r * 64 + ((lk * 8) ^ sw)];
            bf16x8 al = *(const bf16x8*)&As[cur][r * 64 + ((32 + lk * 8) ^ sw)];
            acc[mi] = __builtin_amdgcn_mfma_f32_16x16x32_bf16(ah, bh, acc[mi], 0, 0, 0);
            acc[mi] = __builtin_amdgcn_mfma_f32_16x16x32_bf16(ah, bl, acc[mi], 0, 0, 0);
            acc[mi] = __builtin_amdgcn_mfma_f32_16x16x32_bf16(al, bh, acc[mi], 0, 0, 0);
        }
        __syncthreads();   // drains vmcnt (next buf staged) + frees cur buf
        cur ^= 1;
    }

    // ---- epilogue: Wh store + fused score partials ----
    const int col_g = bn * GBN + wn * 16 + lr;
    const int h = col_g >> 7, d = col_g & (HEAD_DIM - 1);   // h uniform/block
    const float ca = a[d], cb = a[HEAD_DIM + d];
#pragma unroll
    for (int mi = 0; mi < 4; ++mi) {
        float ss[4], sd[4];
#pragma unroll
        for (int r = 0; r < 4; ++r) {
            int row_g = bm * GBM + mi * 16 + lk * 4 + r;
            float v = acc[mi][r];
            Wh[(size_t)row_g * OUT_DIM + col_g] = v;
            ss[r] = v * ca;
            sd[r] = v * cb;
        }
#pragma unroll
        for (int s = 1; s < 16; s <<= 1)
#pragma unroll
            for (int r = 0; r < 4; ++r) {
                ss[r] += __shfl_xor(ss[r], s);
                sd[r] += __shfl_xor(sd[r], s);
            }
        if (lr == 0) {
#pragma unroll
            for (int r = 0; r < 4; ++r) {
                int row_g = bm * GBM + mi * 16 + lk * 4 + r;
                atomicAdd(&s_src[row_g * NUM_HEADS + h], ss[r]);
                atomicAdd(&s_dst[row_g * NUM_HEADS + h], sd[r]);
            }
        }
    }
}

// ---------------------------------------------------------------------------
// Top-16 per adj row.  Fast path: threshold filter (~49/4096 expected),
// packed u64 keys in LDS, 16 wave-argmax rounds over <=2 keys/lane.
// Exact fallback if count outside [16, 128].
// ---------------------------------------------------------------------------
#define TK_THRESH 0.988f
#define TK_CAP 128

__global__ __launch_bounds__(256) void topk_kernel(
    const float* __restrict__ adj, int* __restrict__ topk)
{
    const int wave = threadIdx.x >> 6, lane = threadIdx.x & 63;
    const int row  = blockIdx.x * 4 + wave;
    const float* rp = adj + (size_t)row * N_NODES;
    __shared__ unsigned long long cand[4][TK_CAP];

    float v[64];
#pragma unroll
    for (int i = 0; i < 16; ++i) {
        float4 q = *(const float4*)(rp + i * 256 + lane * 4);
        v[i * 4 + 0] = q.x; v[i * 4 + 1] = q.y; v[i * 4 + 2] = q.z; v[i * 4 + 3] = q.w;
    }
    int* op = topk + (size_t)row * TOP_K;

    const unsigned long long lmask = (1ull << lane) - 1ull;
    int cnt = 0;
#pragma unroll
    for (int s = 0; s < 64; ++s) {
        int g = (s >> 2) * 256 + lane * 4 + (s & 3);
        bool p = v[s] >= TK_THRESH;
        unsigned long long m = __ballot(p);
        if (p) {
            int pos = cnt + __popcll(m & lmask);
            if (pos < TK_CAP) {
                unsigned b  = __float_as_uint(v[s]);
                unsigned mo = b ^ (unsigned)(((int)b >> 31) | 0x80000000);
                cand[wave][pos] =
                    ((unsigned long long)mo << 32) | (unsigned)(N_NODES - 1 - g);
            }
        }
        cnt += __popcll(m);
    }

    if (cnt >= TOP_K && cnt <= TK_CAP) {
        for (int j = cnt + lane; j < TK_CAP; j += 64) cand[wave][j] = 0ull;
        unsigned long long c0 = cand[wave][lane], c1 = cand[wave][lane + 64];
        for (int r = 0; r < TOP_K; ++r) {
            unsigned long long b = c0 > c1 ? c0 : c1;
#pragma unroll
            for (int m = 1; m < 64; m <<= 1) {
                unsigned long long o = __shfl_xor(b, m);
                b = o > b ? o : b;
            }
            if (lane == 0) op[r] = N_NODES - 1 - (int)(unsigned)(b & 0xFFFFFFFFu);
            if (c0 == b) c0 = 0ull;
            if (c1 == b) c1 = 0ull;
        }
    } else {
        for (int r = 0; r < TOP_K; ++r) {
            float bv = -INFINITY; int bg = 0x7fffffff;
#pragma unroll
            for (int s = 0; s < 64; ++s) {
                int g = (s >> 2) * 256 + lane * 4 + (s & 3);
                bool better = (v[s] > bv) || (v[s] == bv && g < bg);
                bv = better ? v[s] : bv;
                bg = better ? g : bg;
            }
#pragma unroll
            for (int m = 1; m < 64; m <<= 1) {
                float ov = __shfl_xor(bv, m);
                int   og = __shfl_xor(bg, m);
                bool better = (ov > bv) || (ov == bv && og < bg);
                bv = better ? ov : bv;
                bg = better ? og : bg;
            }
            if (lane == 0) op[r] = bg;
#pragma unroll
            for (int s = 0; s < 64; ++s) {
                int g = (s >> 2) * 256 + lane * 4 + (s & 3);
                if (g == bg) v[s] = -INFINITY;
            }
        }
    }
}

// ---------------------------------------------------------------------------
// Aggregate: wave-parallel softmax (64 lanes = 16 m x 4 h, stride-4
// butterflies), then gather-weighted sum + ELU.
// ---------------------------------------------------------------------------
__global__ __launch_bounds__(256) void aggregate_kernel(
    const float* __restrict__ Wh, const int* __restrict__ topk,
    const float* __restrict__ s_src, const float* __restrict__ s_dst,
    float* __restrict__ out)
{
    const int i = blockIdx.x, t = threadIdx.x;
    __shared__ int   sidx[TOP_K];
    __shared__ float salpha[TOP_K][NUM_HEADS];

    if (t < 64) {
        int idxv = 0;
        if (t < TOP_K) { idxv = topk[(size_t)i * TOP_K + t]; sidx[t] = idxv; }
        int m = t >> 2, h = t & 3;
        int im = __shfl(idxv, m);
        float e = s_src[i * NUM_HEADS + h] + s_dst[im * NUM_HEADS + h];
        e = (e >= 0.f) ? e : NEG_SLOPE * e;
        float mx = e;
#pragma unroll
        for (int s = 4; s < 64; s <<= 1) mx = fmaxf(mx, __shfl_xor(mx, s));
        float ex = expf(e - mx);
        float sum = ex;
#pragma unroll
        for (int s = 4; s < 64; s <<= 1) sum += __shfl_xor(sum, s);
        salpha[m][h] = ex / sum;
    }
    __syncthreads();

#pragma unroll
    for (int rep = 0; rep < 2; ++rep) {
        int c = rep * 256 + t;          // c = h*128 + d
        int h = c >> 7;
        float acc = 0.f;
#pragma unroll
        for (int m = 0; m < TOP_K; ++m)
            acc += salpha[m][h] * Wh[(size_t)sidx[m] * OUT_DIM + c];
        out[(size_t)i * OUT_DIM + c] = (acc > 0.f) ? acc : (expf(acc) - 1.f);
    }
}

// ---------------------------------------------------------------------------
extern "C" void kernel_launch(void* const* d_in, const int* in_sizes, int n_in,
                              void* d_out, int out_size, void* d_ws, size_t ws_size,
                              hipStream_t stream) {
    const float* x   = (const float*)d_in[0];
    const float* adj = (const float*)d_in[1];
    const float* W   = (const float*)d_in[2];
    const float* a   = (const float*)d_in[3];
    float* out = (float*)d_out;

    char* ws = (char*)d_ws;
    float*          Wh    = (float*)ws;                                  //  8 MB
    unsigned short* xc    = (unsigned short*)(ws + (8u << 20));          // 16 MB
    unsigned short* wc    = (unsigned short*)(ws + (24u << 20));         //  2 MB
    float*          s_src = (float*)(ws + (26u << 20));                  // 64 KB
    float*          s_dst = s_src + N_NODES * NUM_HEADS;                 // 64 KB
    int*            topkb = (int*)(s_dst + N_NODES * NUM_HEADS);         // 256 KB

    // 2048 blocks x-conv + 256 W-conv + 32 zero (s_src+s_dst = 32768 f32)
    prep_kernel<<<2336, 256, 0, stream>>>(x, W, xc, wc, s_src);
    gemm_kernel<<<512, 256, 0, stream>>>(xc, wc, a, Wh, s_src, s_dst);
    topk_kernel<<<N_NODES / 4, 256, 0, stream>>>(adj, topkb);
    aggregate_kernel<<<N_NODES, 256, 0, stream>>>(Wh, topkb, s_src, s_dst, out);
}

// Round 4
// 180.489 us; speedup vs baseline: 1.0037x; 1.0037x over previous
//
#include <hip/hip_runtime.h>
#include <hip/hip_bf16.h>

#define N_NODES 4096
#define IN_DIM 1024
#define OUT_DIM 512
#define NUM_HEADS 4
#define HEAD_DIM 128
#define TOP_K 16
#define NEG_SLOPE 0.2f

typedef __attribute__((ext_vector_type(8))) short bf16x8;
typedef __attribute__((ext_vector_type(4))) float f32x4;

typedef __attribute__((address_space(3))) unsigned as3_u32;
typedef const __attribute__((address_space(1))) unsigned as1_u32;

static __device__ __forceinline__ void gld16(const void* g, void* l) {
    __builtin_amdgcn_global_load_lds((as1_u32*)g, (as3_u32*)l, 16, 0, 0);
}

__device__ __forceinline__ unsigned short f2bf(float f) {
    unsigned u = __float_as_uint(f);
    unsigned r = u + 0x7FFFu + ((u >> 16) & 1u);   // round-to-nearest-even
    return (unsigned short)(r >> 16);
}
__device__ __forceinline__ float bf2f(unsigned short h) {
    return __uint_as_float(((unsigned)h) << 16);
}

// ---------------------------------------------------------------------------
// Prep (fused): f32 -> swizzled hi|lo bf16 for x and W, plus zero-init of
// s_src/s_dst.  Chunk at position c ^ (row&7), row stride 2048 ushorts.
// ---------------------------------------------------------------------------
__device__ __forceinline__ void conv_row(const float* __restrict__ src,
                                         unsigned short* __restrict__ dst, int t)
{
    int row = t >> 7, rem = t & 127, kb = rem >> 2, c = rem & 3;
    const float* s = src + (size_t)row * IN_DIM + kb * 32 + c * 8;
    float4 v0 = *(const float4*)s;
    float4 v1 = *(const float4*)(s + 4);
    float vv[8] = {v0.x, v0.y, v0.z, v0.w, v1.x, v1.y, v1.z, v1.w};
    bf16x8 H, L;
#pragma unroll
    for (int e = 0; e < 8; ++e) {
        unsigned short h = f2bf(vv[e]);
        H[e] = (short)h;
        L[e] = (short)f2bf(vv[e] - bf2f(h));
    }
    int sw = row & 7;
    unsigned short* base = dst + (size_t)row * 2048 + kb * 64;
    *(bf16x8*)(base + ((c ^ sw) << 3))       = H;
    *(bf16x8*)(base + (((c + 4) ^ sw) << 3)) = L;
}

__global__ __launch_bounds__(256) void prep_kernel(
    const float* __restrict__ x, const float* __restrict__ W,
    unsigned short* __restrict__ xc, unsigned short* __restrict__ wc,
    float* __restrict__ szero)
{
    int b = blockIdx.x, tid = threadIdx.x;
    if (b < 2048) {
        conv_row(x, xc, b * 256 + tid);
    } else if (b < 2304) {
        conv_row(W, wc, (b - 2048) * 256 + tid);
    } else {
        int t = (b - 2304) * 256 + tid;
        ((float4*)szero)[t] = (float4){0.f, 0.f, 0.f, 0.f};
    }
}

// ---------------------------------------------------------------------------
// GEMM + fused scores.  Tile 64x64, BK=32, 4 waves.  Depth-2 pipeline:
// 3 LDS buffers, counted s_waitcnt vmcnt(4) so the next-tile loads stay in
// flight ACROSS the barrier (loads never drained to 0 in the main loop).
// XCD swizzle: xcd=id&7 owns bm in [8*xcd,8*xcd+8) x all bn -> 4MB = its L2.
// ---------------------------------------------------------------------------
#define GBM 64
#define GBN 64
#define NT  (IN_DIM / 32)    // 32 K-steps

__global__ __launch_bounds__(256) void gemm_kernel(
    const unsigned short* __restrict__ xc, const unsigned short* __restrict__ wc,
    const float* __restrict__ a, float* __restrict__ Wh,
    float* __restrict__ s_src, float* __restrict__ s_dst)
{
    __shared__ __align__(16) unsigned short As[3][GBM * 64];  // 8 KB each
    __shared__ __align__(16) unsigned short Bs[3][GBN * 64];  // 8 KB each

    const int tid = threadIdx.x;
    const int id  = blockIdx.x;
    const int xcd = id & 7, seq = id >> 3;
    const int bm  = xcd * 8 + (seq >> 3), bn = seq & 7;

    const int wn = tid >> 6, lane = tid & 63;
    const int lr = lane & 15, lk = lane >> 4;

    f32x4 acc[4];
#pragma unroll
    for (int i = 0; i < 4; ++i) acc[i] = (f32x4){0.f, 0.f, 0.f, 0.f};

    // per-thread staging coords (2 chunks of A, 2 of B)
    const int ci0 = tid, ci1 = 256 + tid;

    auto stage = [&](int buf, int kt) {
        size_t koff = (size_t)kt * 128;
        {
            int row = ci0 >> 3, p = ci0 & 7;
            gld16((const char*)xc + ((size_t)(bm * GBM + row) * 4096 + koff + p * 16),
                  (char*)&As[buf][0] + (size_t)ci0 * 16);
        }
        {
            int row = ci1 >> 3, p = ci1 & 7;
            gld16((const char*)xc + ((size_t)(bm * GBM + row) * 4096 + koff + p * 16),
                  (char*)&As[buf][0] + (size_t)ci1 * 16);
        }
        {
            int row = ci0 >> 3, p = ci0 & 7;
            gld16((const char*)wc + ((size_t)(bn * GBN + row) * 4096 + koff + p * 16),
                  (char*)&Bs[buf][0] + (size_t)ci0 * 16);
        }
        {
            int row = ci1 >> 3, p = ci1 & 7;
            gld16((const char*)wc + ((size_t)(bn * GBN + row) * 4096 + koff + p * 16),
                  (char*)&Bs[buf][0] + (size_t)ci1 * 16);
        }
    };

    stage(0, 0);
    stage(1, 1);

    int cur = 0;
    for (int t = 0; t < NT; ++t) {
        // stage-t loads complete; stage-(t+1) loads remain in flight
        if (t < NT - 1) asm volatile("s_waitcnt vmcnt(4)" ::: "memory");
        else            asm volatile("s_waitcnt vmcnt(0)" ::: "memory");
        __builtin_amdgcn_s_barrier();
        asm volatile("" ::: "memory");     // pin LDS reads below the barrier

        if (t + 2 < NT) {
            int nb = cur >= 1 ? cur - 1 : cur + 2;   // (cur+2)%3
            stage(nb, t + 2);
        }

        const unsigned short* Ac = As[cur];
        const unsigned short* Bc = Bs[cur];
        bf16x8 bh, bl;
        {
            int rb = wn * 16 + lr, sw = (rb & 7) << 3;
            bh = *(const bf16x8*)&Bc[rb * 64 + ((lk * 8) ^ sw)];
            bl = *(const bf16x8*)&Bc[rb * 64 + ((32 + lk * 8) ^ sw)];
        }
#pragma unroll
        for (int mi = 0; mi < 4; ++mi) {
            int r = mi * 16 + lr, sw = (r & 7) << 3;
            bf16x8 ah = *(const bf16x8*)&Ac[r * 64 + ((lk * 8) ^ sw)];
            bf16x8 al = *(const bf16x8*)&Ac[r * 64 + ((32 + lk * 8) ^ sw)];
            acc[mi] = __builtin_amdgcn_mfma_f32_16x16x32_bf16(ah, bh, acc[mi], 0, 0, 0);
            acc[mi] = __builtin_amdgcn_mfma_f32_16x16x32_bf16(ah, bl, acc[mi], 0, 0, 0);
            acc[mi] = __builtin_amdgcn_mfma_f32_16x16x32_bf16(al, bh, acc[mi], 0, 0, 0);
        }
        cur = cur == 2 ? 0 : cur + 1;
    }

    // ---- epilogue: Wh store + fused score partials ----
    const int col_g = bn * GBN + wn * 16 + lr;
    const int h = col_g >> 7, d = col_g & (HEAD_DIM - 1);
    const float ca = a[d], cb = a[HEAD_DIM + d];
#pragma unroll
    for (int mi = 0; mi < 4; ++mi) {
        float ss[4], sd[4];
#pragma unroll
        for (int r = 0; r < 4; ++r) {
            int row_g = bm * GBM + mi * 16 + lk * 4 + r;
            float v = acc[mi][r];
            Wh[(size_t)row_g * OUT_DIM + col_g] = v;
            ss[r] = v * ca;
            sd[r] = v * cb;
        }
#pragma unroll
        for (int s = 1; s < 16; s <<= 1)
#pragma unroll
            for (int r = 0; r < 4; ++r) {
                ss[r] += __shfl_xor(ss[r], s);
                sd[r] += __shfl_xor(sd[r], s);
            }
        if (lr == 0) {
#pragma unroll
            for (int r = 0; r < 4; ++r) {
                int row_g = bm * GBM + mi * 16 + lk * 4 + r;
                atomicAdd(&s_src[row_g * NUM_HEADS + h], ss[r]);
                atomicAdd(&s_dst[row_g * NUM_HEADS + h], sd[r]);
            }
        }
    }
}

// ---------------------------------------------------------------------------
// Top-16 per adj row.  Threshold filter fast path + exact fallback.
// ---------------------------------------------------------------------------
#define TK_THRESH 0.988f
#define TK_CAP 128

__global__ __launch_bounds__(256) void topk_kernel(
    const float* __restrict__ adj, int* __restrict__ topk)
{
    const int wave = threadIdx.x >> 6, lane = threadIdx.x & 63;
    const int row  = blockIdx.x * 4 + wave;
    const float* rp = adj + (size_t)row * N_NODES;
    __shared__ unsigned long long cand[4][TK_CAP];

    float v[64];
#pragma unroll
    for (int i = 0; i < 16; ++i) {
        float4 q = *(const float4*)(rp + i * 256 + lane * 4);
        v[i * 4 + 0] = q.x; v[i * 4 + 1] = q.y; v[i * 4 + 2] = q.z; v[i * 4 + 3] = q.w;
    }
    int* op = topk + (size_t)row * TOP_K;

    const unsigned long long lmask = (1ull << lane) - 1ull;
    int cnt = 0;
#pragma unroll
    for (int s = 0; s < 64; ++s) {
        int g = (s >> 2) * 256 + lane * 4 + (s & 3);
        bool p = v[s] >= TK_THRESH;
        unsigned long long m = __ballot(p);
        if (p) {
            int pos = cnt + __popcll(m & lmask);
            if (pos < TK_CAP) {
                unsigned b  = __float_as_uint(v[s]);
                unsigned mo = b ^ (unsigned)(((int)b >> 31) | 0x80000000);
                cand[wave][pos] =
                    ((unsigned long long)mo << 32) | (unsigned)(N_NODES - 1 - g);
            }
        }
        cnt += __popcll(m);
    }

    if (cnt >= TOP_K && cnt <= TK_CAP) {
        for (int j = cnt + lane; j < TK_CAP; j += 64) cand[wave][j] = 0ull;
        unsigned long long c0 = cand[wave][lane], c1 = cand[wave][lane + 64];
        for (int r = 0; r < TOP_K; ++r) {
            unsigned long long b = c0 > c1 ? c0 : c1;
#pragma unroll
            for (int m = 1; m < 64; m <<= 1) {
                unsigned long long o = __shfl_xor(b, m);
                b = o > b ? o : b;
            }
            if (lane == 0) op[r] = N_NODES - 1 - (int)(unsigned)(b & 0xFFFFFFFFu);
            if (c0 == b) c0 = 0ull;
            if (c1 == b) c1 = 0ull;
        }
    } else {
        for (int r = 0; r < TOP_K; ++r) {
            float bv = -INFINITY; int bg = 0x7fffffff;
#pragma unroll
            for (int s = 0; s < 64; ++s) {
                int g = (s >> 2) * 256 + lane * 4 + (s & 3);
                bool better = (v[s] > bv) || (v[s] == bv && g < bg);
                bv = better ? v[s] : bv;
                bg = better ? g : bg;
            }
#pragma unroll
            for (int m = 1; m < 64; m <<= 1) {
                float ov = __shfl_xor(bv, m);
                int   og = __shfl_xor(bg, m);
                bool better = (ov > bv) || (ov == bv && og < bg);
                bv = better ? ov : bv;
                bg = better ? og : bg;
            }
            if (lane == 0) op[r] = bg;
#pragma unroll
            for (int s = 0; s < 64; ++s) {
                int g = (s >> 2) * 256 + lane * 4 + (s & 3);
                if (g == bg) v[s] = -INFINITY;
            }
        }
    }
}

// ---------------------------------------------------------------------------
// Aggregate: wave-parallel softmax, then float4 gather (2 halves x 128
// float4-cols, 8 neighbors each, LDS combine) + ELU.
// ---------------------------------------------------------------------------
__global__ __launch_bounds__(256) void aggregate_kernel(
    const float* __restrict__ Wh, const int* __restrict__ topk,
    const float* __restrict__ s_src, const float* __restrict__ s_dst,
    float* __restrict__ out)
{
    const int i = blockIdx.x, t = threadIdx.x;
    __shared__ int   sidx[TOP_K];
    __shared__ float salpha[TOP_K][NUM_HEADS];
    __shared__ float4 part[128];

    if (t < 64) {
        int idxv = 0;
        if (t < TOP_K) { idxv = topk[(size_t)i * TOP_K + t]; sidx[t] = idxv; }
        int m = t >> 2, h = t & 3;
        int im = __shfl(idxv, m);
        float e = s_src[i * NUM_HEADS + h] + s_dst[im * NUM_HEADS + h];
        e = (e >= 0.f) ? e : NEG_SLOPE * e;
        float mx = e;
#pragma unroll
        for (int s = 4; s < 64; s <<= 1) mx = fmaxf(mx, __shfl_xor(mx, s));
        float ex = expf(e - mx);
        float sum = ex;
#pragma unroll
        for (int s = 4; s < 64; s <<= 1) sum += __shfl_xor(sum, s);
        salpha[m][h] = ex / sum;
    }
    __syncthreads();

    const int c4 = t & 127, half = t >> 7;   // col = c4*4, h = c4>>5
    const int h = c4 >> 5;
    float4 acc = (float4){0.f, 0.f, 0.f, 0.f};
#pragma unroll
    for (int mm = 0; mm < 8; ++mm) {
        int m = half * 8 + mm;
        float al = salpha[m][h];
        float4 v = *(const float4*)(Wh + (size_t)sidx[m] * OUT_DIM + c4 * 4);
        acc.x += al * v.x; acc.y += al * v.y;
        acc.z += al * v.z; acc.w += al * v.w;
    }
    if (half) part[c4] = acc;
    __syncthreads();
    if (!half) {
        float4 o = part[c4];
        acc.x += o.x; acc.y += o.y; acc.z += o.z; acc.w += o.w;
        float4 r;
        r.x = acc.x > 0.f ? acc.x : expf(acc.x) - 1.f;
        r.y = acc.y > 0.f ? acc.y : expf(acc.y) - 1.f;
        r.z = acc.z > 0.f ? acc.z : expf(acc.z) - 1.f;
        r.w = acc.w > 0.f ? acc.w : expf(acc.w) - 1.f;
        *(float4*)(out + (size_t)i * OUT_DIM + c4 * 4) = r;
    }
}

// ---------------------------------------------------------------------------
extern "C" void kernel_launch(void* const* d_in, const int* in_sizes, int n_in,
                              void* d_out, int out_size, void* d_ws, size_t ws_size,
                              hipStream_t stream) {
    const float* x   = (const float*)d_in[0];
    const float* adj = (const float*)d_in[1];
    const float* W   = (const float*)d_in[2];
    const float* a   = (const float*)d_in[3];
    float* out = (float*)d_out;

    char* ws = (char*)d_ws;
    float*          Wh    = (float*)ws;                                  //  8 MB
    unsigned short* xc    = (unsigned short*)(ws + (8u << 20));          // 16 MB
    unsigned short* wc    = (unsigned short*)(ws + (24u << 20));         //  2 MB
    float*          s_src = (float*)(ws + (26u << 20));                  // 64 KB
    float*          s_dst = s_src + N_NODES * NUM_HEADS;                 // 64 KB
    int*            topkb = (int*)(s_dst + N_NODES * NUM_HEADS);         // 256 KB

    prep_kernel<<<2336, 256, 0, stream>>>(x, W, xc, wc, s_src);
    gemm_kernel<<<512, 256, 0, stream>>>(xc, wc, a, Wh, s_src, s_dst);
    topk_kernel<<<N_NODES / 4, 256, 0, stream>>>(adj, topkb);
    aggregate_kernel<<<N_NODES, 256, 0, stream>>>(Wh, topkb, s_src, s_dst, out);
}

// Round 6
// 172.891 us; speedup vs baseline: 1.0478x; 1.0439x over previous
//
#include <hip/hip_runtime.h>
#include <hip/hip_bf16.h>

#define N_NODES 4096
#define IN_DIM 1024
#define OUT_DIM 512
#define NUM_HEADS 4
#define HEAD_DIM 128
#define TOP_K 16
#define NEG_SLOPE 0.2f

typedef __attribute__((ext_vector_type(8))) short bf16x8;
typedef __attribute__((ext_vector_type(4))) float f32x4;

typedef __attribute__((address_space(3))) unsigned as3_u32;
typedef const __attribute__((address_space(1))) unsigned as1_u32;

static __device__ __forceinline__ void gld16(const void* g, void* l) {
    __builtin_amdgcn_global_load_lds((as1_u32*)g, (as3_u32*)l, 16, 0, 0);
}

__device__ __forceinline__ unsigned short f2bf(float f) {
    unsigned u = __float_as_uint(f);
    unsigned r = u + 0x7FFFu + ((u >> 16) & 1u);   // round-to-nearest-even
    return (unsigned short)(r >> 16);
}
__device__ __forceinline__ float bf2f(unsigned short h) {
    return __uint_as_float(((unsigned)h) << 16);
}

// ---------------------------------------------------------------------------
// Prep (fused): f32 -> swizzled hi|lo bf16 for x and W, plus zero-init of
// s_src/s_dst.  Chunk at position c ^ (row&7), row stride 2048 ushorts.
// ---------------------------------------------------------------------------
__device__ __forceinline__ void conv_row(const float* __restrict__ src,
                                         unsigned short* __restrict__ dst, int t)
{
    int row = t >> 7, rem = t & 127, kb = rem >> 2, c = rem & 3;
    const float* s = src + (size_t)row * IN_DIM + kb * 32 + c * 8;
    float4 v0 = *(const float4*)s;
    float4 v1 = *(const float4*)(s + 4);
    float vv[8] = {v0.x, v0.y, v0.z, v0.w, v1.x, v1.y, v1.z, v1.w};
    bf16x8 H, L;
#pragma unroll
    for (int e = 0; e < 8; ++e) {
        unsigned short h = f2bf(vv[e]);
        H[e] = (short)h;
        L[e] = (short)f2bf(vv[e] - bf2f(h));
    }
    int sw = row & 7;
    unsigned short* base = dst + (size_t)row * 2048 + kb * 64;
    *(bf16x8*)(base + ((c ^ sw) << 3))       = H;
    *(bf16x8*)(base + (((c + 4) ^ sw) << 3)) = L;
}

__global__ __launch_bounds__(256) void prep_kernel(
    const float* __restrict__ x, const float* __restrict__ W,
    unsigned short* __restrict__ xc, unsigned short* __restrict__ wc,
    float* __restrict__ szero)
{
    int b = blockIdx.x, tid = threadIdx.x;
    if (b < 2048) {
        conv_row(x, xc, b * 256 + tid);
    } else if (b < 2304) {
        conv_row(W, wc, (b - 2048) * 256 + tid);
    } else {
        int t = (b - 2304) * 256 + tid;
        ((float4*)szero)[t] = (float4){0.f, 0.f, 0.f, 0.f};
    }
}

// ---------------------------------------------------------------------------
// GEMM + fused scores.  Tile 64x64, BK=32, 4 waves.  Depth-2 pipeline over
// SIX STATIC named LDS buffers (A0..A2, B0..B2) with a x3-unrolled body, so
// the compiler's alias analysis can emit PRECISE counted waits (vmcnt(8))
// instead of the vmcnt(0) drain it inserts for runtime-indexed buffers.
// Manual vmcnt(4)-before-barrier gives the cross-wave landing guarantee.
// XCD swizzle: xcd=id&7 owns bm in [8*xcd,8*xcd+8) x all bn -> 4MB = its L2.
// ---------------------------------------------------------------------------
#define GBM 64
#define GBN 64

__global__ __launch_bounds__(256) void gemm_kernel(
    const unsigned short* __restrict__ xc, const unsigned short* __restrict__ wc,
    const float* __restrict__ a, float* __restrict__ Wh,
    float* __restrict__ s_src, float* __restrict__ s_dst)
{
    __shared__ __align__(16) unsigned short A0[GBM * 64];
    __shared__ __align__(16) unsigned short A1[GBM * 64];
    __shared__ __align__(16) unsigned short A2[GBM * 64];
    __shared__ __align__(16) unsigned short B0[GBN * 64];
    __shared__ __align__(16) unsigned short B1[GBN * 64];
    __shared__ __align__(16) unsigned short B2[GBN * 64];

    const int tid = threadIdx.x;
    const int id  = blockIdx.x;
    const int xcd = id & 7, seq = id >> 3;
    const int bm  = xcd * 8 + (seq >> 3), bn = seq & 7;

    const int wn = tid >> 6, lane = tid & 63;
    const int lr = lane & 15, lk = lane >> 4;

    f32x4 acc[4];
#pragma unroll
    for (int i = 0; i < 4; ++i) acc[i] = (f32x4){0.f, 0.f, 0.f, 0.f};

#define STAGE(Abuf, Bbuf, kt) do {                                            \
        size_t koff = (size_t)(kt) * 128;                                     \
        _Pragma("unroll")                                                     \
        for (int q = 0; q < 2; ++q) {                                         \
            int ci = q * 256 + tid;                                           \
            int row = ci >> 3, p = ci & 7;                                    \
            gld16((const char*)xc + ((size_t)(bm * GBM + row) * 4096 + koff + p * 16), \
                  (char*)(Abuf) + (size_t)ci * 16);                           \
            gld16((const char*)wc + ((size_t)(bn * GBN + row) * 4096 + koff + p * 16), \
                  (char*)(Bbuf) + (size_t)ci * 16);                           \
        }                                                                     \
    } while (0)

#define COMPUTE(Abuf, Bbuf) do {                                              \
        int rb = wn * 16 + lr; int swb = rb & 7;                              \
        bf16x8 bh = *(const bf16x8*)&(Bbuf)[rb * 64 + ((lk ^ swb) << 3)];     \
        bf16x8 bl = *(const bf16x8*)&(Bbuf)[rb * 64 + (((4 + lk) ^ swb) << 3)]; \
        __builtin_amdgcn_s_setprio(1);                                        \
        _Pragma("unroll")                                                     \
        for (int mi = 0; mi < 4; ++mi) {                                      \
            int r = mi * 16 + lr; int sw = r & 7;                             \
            bf16x8 ah = *(const bf16x8*)&(Abuf)[r * 64 + ((lk ^ sw) << 3)];   \
            bf16x8 al = *(const bf16x8*)&(Abuf)[r * 64 + (((4 + lk) ^ sw) << 3)]; \
            acc[mi] = __builtin_amdgcn_mfma_f32_16x16x32_bf16(ah, bh, acc[mi], 0, 0, 0); \
            acc[mi] = __builtin_amdgcn_mfma_f32_16x16x32_bf16(ah, bl, acc[mi], 0, 0, 0); \
            acc[mi] = __builtin_amdgcn_mfma_f32_16x16x32_bf16(al, bh, acc[mi], 0, 0, 0); \
        }                                                                     \
        __builtin_amdgcn_s_setprio(0);                                        \
    } while (0)

#define BODY(Ac, Bc, An, Bn, ktn, W) do {                                     \
        asm volatile("s_waitcnt vmcnt(" #W ")" ::: "memory");                 \
        __builtin_amdgcn_s_barrier();                                         \
        asm volatile("" ::: "memory");                                        \
        if ((ktn) < 32) STAGE(An, Bn, ktn);                                   \
        COMPUTE(Ac, Bc);                                                      \
    } while (0)

    STAGE(A0, B0, 0);
    STAGE(A1, B1, 1);

    for (int i = 0; i < 10; ++i) {
        int t = i * 3;
        BODY(A0, B0, A2, B2, t + 2, 4);
        BODY(A1, B1, A0, B0, t + 3, 4);
        BODY(A2, B2, A1, B1, t + 4, 4);
    }
    // tile 30 (buf 0): loads for 30,31 outstanding -> wait to 4, no stage
    BODY(A0, B0, A2, B2, 32, 4);
    // tile 31 (buf 1): only its own loads outstanding -> drain
    asm volatile("s_waitcnt vmcnt(0)" ::: "memory");
    __builtin_amdgcn_s_barrier();
    asm volatile("" ::: "memory");
    COMPUTE(A1, B1);

#undef BODY
#undef COMPUTE
#undef STAGE

    // ---- epilogue: Wh store + fused score partials ----
    const int col_g = bn * GBN + wn * 16 + lr;
    const int h = col_g >> 7, d = col_g & (HEAD_DIM - 1);
    const float ca = a[d], cb = a[HEAD_DIM + d];
#pragma unroll
    for (int mi = 0; mi < 4; ++mi) {
        float ss[4], sd[4];
#pragma unroll
        for (int r = 0; r < 4; ++r) {
            int row_g = bm * GBM + mi * 16 + lk * 4 + r;
            float v = acc[mi][r];
            Wh[(size_t)row_g * OUT_DIM + col_g] = v;
            ss[r] = v * ca;
            sd[r] = v * cb;
        }
#pragma unroll
        for (int s = 1; s < 16; s <<= 1)
#pragma unroll
            for (int r = 0; r < 4; ++r) {
                ss[r] += __shfl_xor(ss[r], s);
                sd[r] += __shfl_xor(sd[r], s);
            }
        if (lr == 0) {
#pragma unroll
            for (int r = 0; r < 4; ++r) {
                int row_g = bm * GBM + mi * 16 + lk * 4 + r;
                atomicAdd(&s_src[row_g * NUM_HEADS + h], ss[r]);
                atomicAdd(&s_dst[row_g * NUM_HEADS + h], sd[r]);
            }
        }
    }
}

// ---------------------------------------------------------------------------
// Top-16 per adj row.  Threshold filter fast path + exact fallback.
// ---------------------------------------------------------------------------
#define TK_THRESH 0.988f
#define TK_CAP 128

__global__ __launch_bounds__(256) void topk_kernel(
    const float* __restrict__ adj, int* __restrict__ topk)
{
    const int wave = threadIdx.x >> 6, lane = threadIdx.x & 63;
    const int row  = blockIdx.x * 4 + wave;
    const float* rp = adj + (size_t)row * N_NODES;
    __shared__ unsigned long long cand[4][TK_CAP];

    float v[64];
#pragma unroll
    for (int i = 0; i < 16; ++i) {
        float4 q = *(const float4*)(rp + i * 256 + lane * 4);
        v[i * 4 + 0] = q.x; v[i * 4 + 1] = q.y; v[i * 4 + 2] = q.z; v[i * 4 + 3] = q.w;
    }
    int* op = topk + (size_t)row * TOP_K;

    const unsigned long long lmask = (1ull << lane) - 1ull;
    int cnt = 0;
#pragma unroll
    for (int s = 0; s < 64; ++s) {
        int g = (s >> 2) * 256 + lane * 4 + (s & 3);
        bool p = v[s] >= TK_THRESH;
        unsigned long long m = __ballot(p);
        if (p) {
            int pos = cnt + __popcll(m & lmask);
            if (pos < TK_CAP) {
                unsigned b  = __float_as_uint(v[s]);
                unsigned mo = b ^ (unsigned)(((int)b >> 31) | 0x80000000);
                cand[wave][pos] =
                    ((unsigned long long)mo << 32) | (unsigned)(N_NODES - 1 - g);
            }
        }
        cnt += __popcll(m);
    }

    if (cnt >= TOP_K && cnt <= TK_CAP) {
        for (int j = cnt + lane; j < TK_CAP; j += 64) cand[wave][j] = 0ull;
        unsigned long long c0 = cand[wave][lane], c1 = cand[wave][lane + 64];
        for (int r = 0; r < TOP_K; ++r) {
            unsigned long long b = c0 > c1 ? c0 : c1;
#pragma unroll
            for (int m = 1; m < 64; m <<= 1) {
                unsigned long long o = __shfl_xor(b, m);
                b = o > b ? o : b;
            }
            if (lane == 0) op[r] = N_NODES - 1 - (int)(unsigned)(b & 0xFFFFFFFFu);
            if (c0 == b) c0 = 0ull;
            if (c1 == b) c1 = 0ull;
        }
    } else {
        for (int r = 0; r < TOP_K; ++r) {
            float bv = -INFINITY; int bg = 0x7fffffff;
#pragma unroll
            for (int s = 0; s < 64; ++s) {
                int g = (s >> 2) * 256 + lane * 4 + (s & 3);
                bool better = (v[s] > bv) || (v[s] == bv && g < bg);
                bv = better ? v[s] : bv;
                bg = better ? g : bg;
            }
#pragma unroll
            for (int m = 1; m < 64; m <<= 1) {
                float ov = __shfl_xor(bv, m);
                int   og = __shfl_xor(bg, m);
                bool better = (ov > bv) || (ov == bv && og < bg);
                bv = better ? ov : bv;
                bg = better ? og : bg;
            }
            if (lane == 0) op[r] = bg;
#pragma unroll
            for (int s = 0; s < 64; ++s) {
                int g = (s >> 2) * 256 + lane * 4 + (s & 3);
                if (g == bg) v[s] = -INFINITY;
            }
        }
    }
}

// ---------------------------------------------------------------------------
// Aggregate: wave-parallel softmax, then float4 gather (2 halves x 128
// float4-cols, 8 neighbors each, LDS combine) + ELU.
// ---------------------------------------------------------------------------
__global__ __launch_bounds__(256) void aggregate_kernel(
    const float* __restrict__ Wh, const int* __restrict__ topk,
    const float* __restrict__ s_src, const float* __restrict__ s_dst,
    float* __restrict__ out)
{
    const int i = blockIdx.x, t = threadIdx.x;
    __shared__ int   sidx[TOP_K];
    __shared__ float salpha[TOP_K][NUM_HEADS];
    __shared__ float4 part[128];

    if (t < 64) {
        int idxv = 0;
        if (t < TOP_K) { idxv = topk[(size_t)i * TOP_K + t]; sidx[t] = idxv; }
        int m = t >> 2, h = t & 3;
        int im = __shfl(idxv, m);
        float e = s_src[i * NUM_HEADS + h] + s_dst[im * NUM_HEADS + h];
        e = (e >= 0.f) ? e : NEG_SLOPE * e;
        float mx = e;
#pragma unroll
        for (int s = 4; s < 64; s <<= 1) mx = fmaxf(mx, __shfl_xor(mx, s));
        float ex = expf(e - mx);
        float sum = ex;
#pragma unroll
        for (int s = 4; s < 64; s <<= 1) sum += __shfl_xor(sum, s);
        salpha[m][h] = ex / sum;
    }
    __syncthreads();

    const int c4 = t & 127, half = t >> 7;   // col = c4*4, h = c4>>5
    const int h = c4 >> 5;
    float4 acc = (float4){0.f, 0.f, 0.f, 0.f};
#pragma unroll
    for (int mm = 0; mm < 8; ++mm) {
        int m = half * 8 + mm;
        float al = salpha[m][h];
        float4 v = *(const float4*)(Wh + (size_t)sidx[m] * OUT_DIM + c4 * 4);
        acc.x += al * v.x; acc.y += al * v.y;
        acc.z += al * v.z; acc.w += al * v.w;
    }
    if (half) part[c4] = acc;
    __syncthreads();
    if (!half) {
        float4 o = part[c4];
        acc.x += o.x; acc.y += o.y; acc.z += o.z; acc.w += o.w;
        float4 r;
        r.x = acc.x > 0.f ? acc.x : expf(acc.x) - 1.f;
        r.y = acc.y > 0.f ? acc.y : expf(acc.y) - 1.f;
        r.z = acc.z > 0.f ? acc.z : expf(acc.z) - 1.f;
        r.w = acc.w > 0.f ? acc.w : expf(acc.w) - 1.f;
        *(float4*)(out + (size_t)i * OUT_DIM + c4 * 4) = r;
    }
}

// ---------------------------------------------------------------------------
extern "C" void kernel_launch(void* const* d_in, const int* in_sizes, int n_in,
                              void* d_out, int out_size, void* d_ws, size_t ws_size,
                              hipStream_t stream) {
    const float* x   = (const float*)d_in[0];
    const float* adj = (const float*)d_in[1];
    const float* W   = (const float*)d_in[2];
    const float* a   = (const float*)d_in[3];
    float* out = (float*)d_out;

    char* ws = (char*)d_ws;
    float*          Wh    = (float*)ws;                                  //  8 MB
    unsigned short* xc    = (unsigned short*)(ws + (8u << 20));          // 16 MB
    unsigned short* wc    = (unsigned short*)(ws + (24u << 20));         //  2 MB
    float*          s_src = (float*)(ws + (26u << 20));                  // 64 KB
    float*          s_dst = s_src + N_NODES * NUM_HEADS;                 // 64 KB
    int*            topkb = (int*)(s_dst + N_NODES * NUM_HEADS);         // 256 KB

    prep_kernel<<<2336, 256, 0, stream>>>(x, W, xc, wc, s_src);
    gemm_kernel<<<512, 256, 0, stream>>>(xc, wc, a, Wh, s_src, s_dst);
    topk_kernel<<<N_NODES / 4, 256, 0, stream>>>(adj, topkb);
    aggregate_kernel<<<N_NODES, 256, 0, stream>>>(Wh, topkb, s_src, s_dst, out);
}

// Round 7
// 158.159 us; speedup vs baseline: 1.1454x; 1.0931x over previous
//
#include <hip/hip_runtime.h>
#include <hip/hip_bf16.h>

#define N_NODES 4096
#define IN_DIM 1024
#define OUT_DIM 512
#define NUM_HEADS 4
#define HEAD_DIM 128
#define TOP_K 16
#define NEG_SLOPE 0.2f

typedef __attribute__((ext_vector_type(8))) short bf16x8;
typedef __attribute__((ext_vector_type(4))) float f32x4;

typedef __attribute__((address_space(3))) unsigned as3_u32;
typedef const __attribute__((address_space(1))) unsigned as1_u32;

static __device__ __forceinline__ void gld16(const void* g, void* l) {
    __builtin_amdgcn_global_load_lds((as1_u32*)g, (as3_u32*)l, 16, 0, 0);
}

__device__ __forceinline__ unsigned short f2bf(float f) {
    unsigned u = __float_as_uint(f);
    unsigned r = u + 0x7FFFu + ((u >> 16) & 1u);   // round-to-nearest-even
    return (unsigned short)(r >> 16);
}
__device__ __forceinline__ float bf2f(unsigned short h) {
    return __uint_as_float(((unsigned)h) << 16);
}

// ---------------------------------------------------------------------------
// Prep (fused): f32 -> swizzled hi|lo bf16 for x and W, plus zero-init of
// s_src/s_dst.  Chunk at position c ^ (row&7), row stride 2048 ushorts.
// ---------------------------------------------------------------------------
__device__ __forceinline__ void conv_row(const float* __restrict__ src,
                                         unsigned short* __restrict__ dst, int t)
{
    int row = t >> 7, rem = t & 127, kb = rem >> 2, c = rem & 3;
    const float* s = src + (size_t)row * IN_DIM + kb * 32 + c * 8;
    float4 v0 = *(const float4*)s;
    float4 v1 = *(const float4*)(s + 4);
    float vv[8] = {v0.x, v0.y, v0.z, v0.w, v1.x, v1.y, v1.z, v1.w};
    bf16x8 H, L;
#pragma unroll
    for (int e = 0; e < 8; ++e) {
        unsigned short h = f2bf(vv[e]);
        H[e] = (short)h;
        L[e] = (short)f2bf(vv[e] - bf2f(h));
    }
    int sw = row & 7;
    unsigned short* base = dst + (size_t)row * 2048 + kb * 64;
    *(bf16x8*)(base + ((c ^ sw) << 3))       = H;
    *(bf16x8*)(base + (((c + 4) ^ sw) << 3)) = L;
}

__global__ __launch_bounds__(256) void prep_kernel(
    const float* __restrict__ x, const float* __restrict__ W,
    unsigned short* __restrict__ xc, unsigned short* __restrict__ wc,
    float* __restrict__ szero)
{
    int b = blockIdx.x, tid = threadIdx.x;
    if (b < 2048) {
        conv_row(x, xc, b * 256 + tid);
    } else if (b < 2304) {
        conv_row(W, wc, (b - 2048) * 256 + tid);
    } else {
        int t = (b - 2304) * 256 + tid;
        ((float4*)szero)[t] = (float4){0.f, 0.f, 0.f, 0.f};
    }
}

// ---------------------------------------------------------------------------
// GEMM + fused scores.  Tile 128x64, BK=32, 4 waves (2x2), wave-tile 64x32:
// 12 ds_read_b128 -> 24 MFMA per wave-ktstep = 32 FLOP/LDS-byte (parity with
// the 128 B/cyc LDS pipe, vs 19.6 for the old 64x16 wave-tile).  Depth-2
// pipeline, SIX static named LDS buffers, counted vmcnt(6) across barriers.
// XCD swizzle: xcd=id&7 owns bm in [4*xcd,4*xcd+4) x all bn -> 4MB = its L2.
// Wh is stored as bf16 (only the aggregate gather consumes it).
// ---------------------------------------------------------------------------
#define GBM 128
#define GBN 64

__global__ __launch_bounds__(256) void gemm_kernel(
    const unsigned short* __restrict__ xc, const unsigned short* __restrict__ wc,
    const float* __restrict__ a, unsigned short* __restrict__ Whb,
    float* __restrict__ s_src, float* __restrict__ s_dst)
{
    __shared__ __align__(16) unsigned short A0[GBM * 64];   // 16 KB each
    __shared__ __align__(16) unsigned short A1[GBM * 64];
    __shared__ __align__(16) unsigned short A2[GBM * 64];
    __shared__ __align__(16) unsigned short B0[GBN * 64];   //  8 KB each
    __shared__ __align__(16) unsigned short B1[GBN * 64];
    __shared__ __align__(16) unsigned short B2[GBN * 64];

    const int tid = threadIdx.x;
    const int id  = blockIdx.x;               // 256 blocks
    const int xcd = id & 7, seq = id >> 3;    // seq 0..31
    const int bm  = xcd * 4 + (seq >> 3), bn = seq & 7;

    const int wave = tid >> 6, lane = tid & 63;
    const int wm = wave >> 1, wn = wave & 1;  // 2x2 wave grid
    const int lr = lane & 15, lk = lane >> 4;

    f32x4 acc[4][2];
#pragma unroll
    for (int i = 0; i < 4; ++i)
#pragma unroll
        for (int j = 0; j < 2; ++j) acc[i][j] = (f32x4){0.f, 0.f, 0.f, 0.f};

#define STAGE(Abuf, Bbuf, kt) do {                                            \
        size_t koff = (size_t)(kt) * 128;                                     \
        _Pragma("unroll")                                                     \
        for (int q = 0; q < 4; ++q) {          /* A: 16 KB = 1024 chunks */   \
            int ci = q * 256 + tid;                                           \
            int row = ci >> 3, p = ci & 7;                                    \
            gld16((const char*)xc + ((size_t)(bm * GBM + row) * 4096 + koff + p * 16), \
                  (char*)(Abuf) + (size_t)ci * 16);                           \
        }                                                                     \
        _Pragma("unroll")                                                     \
        for (int q = 0; q < 2; ++q) {          /* B: 8 KB = 512 chunks */     \
            int ci = q * 256 + tid;                                           \
            int row = ci >> 3, p = ci & 7;                                    \
            gld16((const char*)wc + ((size_t)(bn * GBN + row) * 4096 + koff + p * 16), \
                  (char*)(Bbuf) + (size_t)ci * 16);                           \
        }                                                                     \
    } while (0)

#define COMPUTE(Abuf, Bbuf) do {                                              \
        bf16x8 bh[2], bl[2];                                                  \
        _Pragma("unroll")                                                     \
        for (int ni = 0; ni < 2; ++ni) {                                      \
            int rb = wn * 32 + ni * 16 + lr; int swb = rb & 7;                \
            bh[ni] = *(const bf16x8*)&(Bbuf)[rb * 64 + ((lk ^ swb) << 3)];    \
            bl[ni] = *(const bf16x8*)&(Bbuf)[rb * 64 + (((4 + lk) ^ swb) << 3)]; \
        }                                                                     \
        __builtin_amdgcn_s_setprio(1);                                        \
        _Pragma("unroll")                                                     \
        for (int mi = 0; mi < 4; ++mi) {                                      \
            int r = wm * 64 + mi * 16 + lr; int sw = r & 7;                   \
            bf16x8 ah = *(const bf16x8*)&(Abuf)[r * 64 + ((lk ^ sw) << 3)];   \
            bf16x8 al = *(const bf16x8*)&(Abuf)[r * 64 + (((4 + lk) ^ sw) << 3)]; \
            _Pragma("unroll")                                                 \
            for (int ni = 0; ni < 2; ++ni) {                                  \
                acc[mi][ni] = __builtin_amdgcn_mfma_f32_16x16x32_bf16(ah, bh[ni], acc[mi][ni], 0, 0, 0); \
                acc[mi][ni] = __builtin_amdgcn_mfma_f32_16x16x32_bf16(ah, bl[ni], acc[mi][ni], 0, 0, 0); \
                acc[mi][ni] = __builtin_amdgcn_mfma_f32_16x16x32_bf16(al, bh[ni], acc[mi][ni], 0, 0, 0); \
            }                                                                 \
        }                                                                     \
        __builtin_amdgcn_s_setprio(0);                                        \
    } while (0)

#define BODY(Ac, Bc, An, Bn, ktn, W) do {                                     \
        asm volatile("s_waitcnt vmcnt(" #W ")" ::: "memory");                 \
        __builtin_amdgcn_s_barrier();                                         \
        asm volatile("" ::: "memory");                                        \
        if ((ktn) < 32) STAGE(An, Bn, ktn);                                   \
        COMPUTE(Ac, Bc);                                                      \
    } while (0)

    STAGE(A0, B0, 0);
    STAGE(A1, B1, 1);

    for (int i = 0; i < 10; ++i) {
        int t = i * 3;
        BODY(A0, B0, A2, B2, t + 2, 6);
        BODY(A1, B1, A0, B0, t + 3, 6);
        BODY(A2, B2, A1, B1, t + 4, 6);
    }
    // tile 30 (buf 0): tile-31 loads stay outstanding
    BODY(A0, B0, A2, B2, 32, 6);
    // tile 31 (buf 1): drain
    asm volatile("s_waitcnt vmcnt(0)" ::: "memory");
    __builtin_amdgcn_s_barrier();
    asm volatile("" ::: "memory");
    COMPUTE(A1, B1);

#undef BODY
#undef COMPUTE
#undef STAGE

    // ---- epilogue: bf16 Wh store + fused score partials (f32 precision) ----
    const int h = bn >> 1;                     // head uniform per block
    float ca[2], cb[2];
#pragma unroll
    for (int ni = 0; ni < 2; ++ni) {
        int dcol = (bn & 1) * 64 + wn * 32 + ni * 16 + lr;
        ca[ni] = a[dcol];
        cb[ni] = a[HEAD_DIM + dcol];
    }
#pragma unroll
    for (int mi = 0; mi < 4; ++mi) {
        float ss[4] = {0.f, 0.f, 0.f, 0.f}, sd[4] = {0.f, 0.f, 0.f, 0.f};
#pragma unroll
        for (int ni = 0; ni < 2; ++ni) {
            int col_g = bn * GBN + wn * 32 + ni * 16 + lr;
#pragma unroll
            for (int r = 0; r < 4; ++r) {
                int row_g = bm * GBM + wm * 64 + mi * 16 + lk * 4 + r;
                float v = acc[mi][ni][r];
                Whb[(size_t)row_g * OUT_DIM + col_g] = f2bf(v);
                ss[r] += v * ca[ni];
                sd[r] += v * cb[ni];
            }
        }
#pragma unroll
        for (int s = 1; s < 16; s <<= 1)
#pragma unroll
            for (int r = 0; r < 4; ++r) {
                ss[r] += __shfl_xor(ss[r], s);
                sd[r] += __shfl_xor(sd[r], s);
            }
        if (lr == 0) {
#pragma unroll
            for (int r = 0; r < 4; ++r) {
                int row_g = bm * GBM + wm * 64 + mi * 16 + lk * 4 + r;
                atomicAdd(&s_src[row_g * NUM_HEADS + h], ss[r]);
                atomicAdd(&s_dst[row_g * NUM_HEADS + h], sd[r]);
            }
        }
    }
}

// ---------------------------------------------------------------------------
// Top-16 per adj row.  Threshold filter fast path + exact fallback.
// ---------------------------------------------------------------------------
#define TK_THRESH 0.988f
#define TK_CAP 128

__global__ __launch_bounds__(256) void topk_kernel(
    const float* __restrict__ adj, int* __restrict__ topk)
{
    const int wave = threadIdx.x >> 6, lane = threadIdx.x & 63;
    const int row  = blockIdx.x * 4 + wave;
    const float* rp = adj + (size_t)row * N_NODES;
    __shared__ unsigned long long cand[4][TK_CAP];

    float v[64];
#pragma unroll
    for (int i = 0; i < 16; ++i) {
        float4 q = *(const float4*)(rp + i * 256 + lane * 4);
        v[i * 4 + 0] = q.x; v[i * 4 + 1] = q.y; v[i * 4 + 2] = q.z; v[i * 4 + 3] = q.w;
    }
    int* op = topk + (size_t)row * TOP_K;

    const unsigned long long lmask = (1ull << lane) - 1ull;
    int cnt = 0;
#pragma unroll
    for (int s = 0; s < 64; ++s) {
        int g = (s >> 2) * 256 + lane * 4 + (s & 3);
        bool p = v[s] >= TK_THRESH;
        unsigned long long m = __ballot(p);
        if (p) {
            int pos = cnt + __popcll(m & lmask);
            if (pos < TK_CAP) {
                unsigned b  = __float_as_uint(v[s]);
                unsigned mo = b ^ (unsigned)(((int)b >> 31) | 0x80000000);
                cand[wave][pos] =
                    ((unsigned long long)mo << 32) | (unsigned)(N_NODES - 1 - g);
            }
        }
        cnt += __popcll(m);
    }

    if (cnt >= TOP_K && cnt <= TK_CAP) {
        for (int j = cnt + lane; j < TK_CAP; j += 64) cand[wave][j] = 0ull;
        unsigned long long c0 = cand[wave][lane], c1 = cand[wave][lane + 64];
        for (int r = 0; r < TOP_K; ++r) {
            unsigned long long b = c0 > c1 ? c0 : c1;
#pragma unroll
            for (int m = 1; m < 64; m <<= 1) {
                unsigned long long o = __shfl_xor(b, m);
                b = o > b ? o : b;
            }
            if (lane == 0) op[r] = N_NODES - 1 - (int)(unsigned)(b & 0xFFFFFFFFu);
            if (c0 == b) c0 = 0ull;
            if (c1 == b) c1 = 0ull;
        }
    } else {
        for (int r = 0; r < TOP_K; ++r) {
            float bv = -INFINITY; int bg = 0x7fffffff;
#pragma unroll
            for (int s = 0; s < 64; ++s) {
                int g = (s >> 2) * 256 + lane * 4 + (s & 3);
                bool better = (v[s] > bv) || (v[s] == bv && g < bg);
                bv = better ? v[s] : bv;
                bg = better ? g : bg;
            }
#pragma unroll
            for (int m = 1; m < 64; m <<= 1) {
                float ov = __shfl_xor(bv, m);
                int   og = __shfl_xor(bg, m);
                bool better = (ov > bv) || (ov == bv && og < bg);
                bv = better ? ov : bv;
                bg = better ? og : bg;
            }
            if (lane == 0) op[r] = bg;
#pragma unroll
            for (int s = 0; s < 64; ++s) {
                int g = (s >> 2) * 256 + lane * 4 + (s & 3);
                if (g == bg) v[s] = -INFINITY;
            }
        }
    }
}

// ---------------------------------------------------------------------------
// Aggregate (bf16 Wh): wave-parallel softmax, then gather with 4 neighbor-
// groups x 64 col-octets (16B bf16x8 loads), conflict-free part[3][8][64]
// combine, ELU, f32 store.
// ---------------------------------------------------------------------------
__global__ __launch_bounds__(256) void aggregate_kernel(
    const unsigned short* __restrict__ Whb, const int* __restrict__ topk,
    const float* __restrict__ s_src, const float* __restrict__ s_dst,
    float* __restrict__ out)
{
    const int i = blockIdx.x, t = threadIdx.x;
    __shared__ int   sidx[TOP_K];
    __shared__ float salpha[TOP_K][NUM_HEADS];
    __shared__ float part[3][8][64];

    if (t < 64) {
        int idxv = 0;
        if (t < TOP_K) { idxv = topk[(size_t)i * TOP_K + t]; sidx[t] = idxv; }
        int m = t >> 2, h = t & 3;
        int im = __shfl(idxv, m);
        float e = s_src[i * NUM_HEADS + h] + s_dst[im * NUM_HEADS + h];
        e = (e >= 0.f) ? e : NEG_SLOPE * e;
        float mx = e;
#pragma unroll
        for (int s = 4; s < 64; s <<= 1) mx = fmaxf(mx, __shfl_xor(mx, s));
        float ex = expf(e - mx);
        float sum = ex;
#pragma unroll
        for (int s = 4; s < 64; s <<= 1) sum += __shfl_xor(sum, s);
        salpha[m][h] = ex / sum;
    }
    __syncthreads();

    const int g = t >> 6, o = t & 63;       // group g: neighbors 4g..4g+3
    const int h = o >> 4;                   // cols 8o..8o+7 all in head h
    float acc8[8] = {0.f, 0.f, 0.f, 0.f, 0.f, 0.f, 0.f, 0.f};
#pragma unroll
    for (int q = 0; q < 4; ++q) {
        int m = g * 4 + q;
        float al = salpha[m][h];
        bf16x8 v = *(const bf16x8*)&Whb[(size_t)sidx[m] * OUT_DIM + o * 8];
#pragma unroll
        for (int e = 0; e < 8; ++e)
            acc8[e] += al * bf2f((unsigned short)v[e]);
    }
    if (g) {
#pragma unroll
        for (int e = 0; e < 8; ++e) part[g - 1][e][o] = acc8[e];
    }
    __syncthreads();
    if (!g) {
        float r8[8];
#pragma unroll
        for (int e = 0; e < 8; ++e) {
            float s = acc8[e] + part[0][e][o] + part[1][e][o] + part[2][e][o];
            r8[e] = s > 0.f ? s : expf(s) - 1.f;
        }
        float4 lo = (float4){r8[0], r8[1], r8[2], r8[3]};
        float4 hi = (float4){r8[4], r8[5], r8[6], r8[7]};
        *(float4*)(out + (size_t)i * OUT_DIM + o * 8)     = lo;
        *(float4*)(out + (size_t)i * OUT_DIM + o * 8 + 4) = hi;
    }
}

// ---------------------------------------------------------------------------
extern "C" void kernel_launch(void* const* d_in, const int* in_sizes, int n_in,
                              void* d_out, int out_size, void* d_ws, size_t ws_size,
                              hipStream_t stream) {
    const float* x   = (const float*)d_in[0];
    const float* adj = (const float*)d_in[1];
    const float* W   = (const float*)d_in[2];
    const float* a   = (const float*)d_in[3];
    float* out = (float*)d_out;

    char* ws = (char*)d_ws;
    unsigned short* Whb   = (unsigned short*)ws;                         //  4 MB
    unsigned short* xc    = (unsigned short*)(ws + (8u << 20));          // 16 MB
    unsigned short* wc    = (unsigned short*)(ws + (24u << 20));         //  2 MB
    float*          s_src = (float*)(ws + (26u << 20));                  // 64 KB
    float*          s_dst = s_src + N_NODES * NUM_HEADS;                 // 64 KB
    int*            topkb = (int*)(s_dst + N_NODES * NUM_HEADS);         // 256 KB

    prep_kernel<<<2336, 256, 0, stream>>>(x, W, xc, wc, s_src);
    gemm_kernel<<<256, 256, 0, stream>>>(xc, wc, a, Whb, s_src, s_dst);
    topk_kernel<<<N_NODES / 4, 256, 0, stream>>>(adj, topkb);
    aggregate_kernel<<<N_NODES, 256, 0, stream>>>(Whb, topkb, s_src, s_dst, out);
}